// Round 4
// baseline (874.615 us; speedup 1.0000x reference)
//
#include <hip/hip_runtime.h>
#include <stdint.h>

#define NNODES  200000
#define NEDGES  400000
#define NGRAPHS 4000
#define NLAYERS 5
#define BN_EPS  1e-5f

typedef __attribute__((ext_vector_type(8))) short short8;
typedef __attribute__((ext_vector_type(4))) float f32x4;

__device__ __forceinline__ unsigned int f2bf(float f) {
    unsigned int u = __float_as_uint(f);
    return (u + 0x7fffu + ((u >> 16) & 1u)) >> 16;
}
__device__ __forceinline__ float bf2f(unsigned int b) {
    return __uint_as_float(b << 16);
}

// ---------------- graph prep ----------------

__global__ void k_init(int* __restrict__ cnt, int* __restrict__ cursor, float* __restrict__ stats) {
    int i = blockIdx.x * 256 + threadIdx.x;
    if (i < NNODES) { cnt[i] = 0; cursor[i] = 0; }
    if (i < NLAYERS * 256) stats[i] = 0.f;
}

__global__ void k_count(const int* __restrict__ ei, int* __restrict__ cnt) {
    int e = blockIdx.x * 256 + threadIdx.x;
    if (e < NEDGES) atomicAdd(&cnt[ei[NEDGES + e]], 1);
}

__global__ void k_dinv(const int* __restrict__ cnt, float* __restrict__ dinv) {
    int v = blockIdx.x * 256 + threadIdx.x;
    if (v < NNODES) dinv[v] = rsqrtf((float)cnt[v] + 1.0f);
}

__global__ __launch_bounds__(256) void k_scan1(const int* __restrict__ cnt,
                                               int* __restrict__ roff, int* __restrict__ bsum) {
    __shared__ int s[256];
    int t = threadIdx.x;
    int v = blockIdx.x * 256 + t;
    int val = (v < NNODES) ? cnt[v] : 0;
    s[t] = val; __syncthreads();
    int sum = val;
    for (int o = 1; o < 256; o <<= 1) {
        int tmp = (t >= o) ? s[t - o] : 0;
        __syncthreads();
        sum += tmp; s[t] = sum;
        __syncthreads();
    }
    if (v < NNODES) roff[v] = sum - val;       // exclusive within block
    if (t == 255) bsum[blockIdx.x] = s[255];
}

__global__ __launch_bounds__(1024) void k_scan2(int* __restrict__ bsum, int nb) {
    __shared__ int s[1024];
    int t = threadIdx.x;
    int val = (t < nb) ? bsum[t] : 0;
    s[t] = val; __syncthreads();
    int sum = val;
    for (int o = 1; o < 1024; o <<= 1) {
        int tmp = (t >= o) ? s[t - o] : 0;
        __syncthreads();
        sum += tmp; s[t] = sum;
        __syncthreads();
    }
    if (t < nb) bsum[t] = sum - val;           // exclusive block offsets
}

__global__ void k_scan3(int* __restrict__ roff, const int* __restrict__ bsum) {
    int v = blockIdx.x * 256 + threadIdx.x;
    if (v < NNODES) roff[v] += bsum[blockIdx.x];
    if (v == 0) roff[NNODES] = NEDGES;
}

__global__ void k_fill(const int* __restrict__ ei, const float* __restrict__ dinv,
                       const int* __restrict__ roff, int* __restrict__ cursor,
                       int2* __restrict__ cedge) {
    int e = blockIdx.x * 256 + threadIdx.x;
    if (e >= NEDGES) return;
    int s = ei[e], d = ei[NEDGES + e];
    int pos = atomicAdd(&cursor[d], 1);
    int idx = roff[d] + pos;
    int2 ed; ed.x = s; ed.y = __float_as_int(dinv[s] * dinv[d]);
    cedge[idx] = ed;
}

__global__ void k_ranges(const int* __restrict__ batch, int* __restrict__ gstart) {
    int v = blockIdx.x * 256 + threadIdx.x;
    if (v >= NNODES) return;
    int b = batch[v];
    if (v == 0) {
        for (int g = 0; g <= b; ++g) gstart[g] = 0;
    } else {
        int pb = batch[v - 1];
        for (int g = pb + 1; g <= b; ++g) gstart[g] = v;
    }
    if (v == NNODES - 1) {
        for (int g = b + 1; g <= NGRAPHS; ++g) gstart[g] = NNODES;
    }
}

// transpose + bf16-convert + swizzle layer weights WT[n][k]=W[k][n] (256B rows),
// and Wx -> WxT[n][k0..63] zero-padded (128B rows).
__global__ void k_wtrans(const float* __restrict__ Wg, const float* __restrict__ Wx,
                         char* __restrict__ wt, char* __restrict__ wxt) {
    int idx = blockIdx.x * 256 + threadIdx.x;
    if (idx < NLAYERS * 16384) {
        int l = idx >> 14;
        int rem = idx & 16383;
        int n = rem >> 7;
        int k = rem & 127;
        float v = Wg[l * 16384 + k * 128 + n];
        char* img = wt + l * 32768;
        *(unsigned short*)(img + (n << 8) + ((k << 1) ^ ((n & 7) << 4))) = (unsigned short)f2bf(v);
    } else if (idx < NLAYERS * 16384 + 8192) {
        int j = idx - NLAYERS * 16384;
        int n = j >> 6;
        int k = j & 63;
        float v = (k < 40) ? Wx[k * 128 + n] : 0.f;
        *(unsigned short*)(wxt + (n << 7) + ((k << 1) ^ ((n & 7) << 4))) = (unsigned short)f2bf(v);
    }
}

// ---------------- input projection (MFMA): h0 = bf16(x @ Wx + bx) ----------------
// A staged in LDS (16 KB); B fragments read directly from L2-resident swizzled image.

__global__ __launch_bounds__(256) void k_inproj(const float* __restrict__ x,
                                                const char* __restrict__ wxt,
                                                const float* __restrict__ bx,
                                                unsigned short* __restrict__ out) {
    __shared__ char As[16384];   // 128 rows * 128 B
    const int tid = threadIdx.x;
    const int m0 = blockIdx.x << 7;

    { // stage A: 16 threads per row cover k 0..63 (4 each), zero-pad k>=40
        const int kq = (tid & 15) << 2;   // 0,4,...,60
        const int r0 = tid >> 4;          // 0..15
        #pragma unroll
        for (int it = 0; it < 8; ++it) {
            const int r = r0 + (it << 4);
            const int grow = m0 + r;
            float x0 = 0.f, x1 = 0.f, x2 = 0.f, x3 = 0.f;
            if (kq < 40 && grow < NNODES) {
                const float4 v = *(const float4*)(x + (size_t)grow * 40 + kq);
                x0 = v.x; x1 = v.y; x2 = v.z; x3 = v.w;
            }
            uint2 p;
            p.x = f2bf(x0) | (f2bf(x1) << 16);
            p.y = f2bf(x2) | (f2bf(x3) << 16);
            *(uint2*)(As + (r << 7) + ((kq << 1) ^ ((r & 7) << 4))) = p;
        }
    }
    __syncthreads();

    const int lane = tid & 63;
    const int wid = tid >> 6;
    const int l15 = lane & 15;
    const int lq = lane >> 4;

    const f32x4 zero = {0.f, 0.f, 0.f, 0.f};
    f32x4 acc[2][8];
    #pragma unroll
    for (int i = 0; i < 2; ++i)
        #pragma unroll
        for (int j = 0; j < 8; ++j) acc[i][j] = zero;

    #pragma unroll
    for (int kk = 0; kk < 2; ++kk) {
        const int kb = (kk << 6) + (lq << 4);
        short8 afr[2];
        #pragma unroll
        for (int rt = 0; rt < 2; ++rt) {
            const int r = (wid << 5) + (rt << 4) + l15;
            afr[rt] = *(const short8*)(As + (r << 7) + (kb ^ ((r & 7) << 4)));
        }
        #pragma unroll
        for (int ct = 0; ct < 8; ++ct) {
            const int n = (ct << 4) + l15;
            const short8 bfr = *(const short8*)(wxt + (n << 7) + (kb ^ ((n & 7) << 4)));
            acc[0][ct] = __builtin_amdgcn_mfma_f32_16x16x32_bf16(afr[0], bfr, acc[0][ct], 0, 0, 0);
            acc[1][ct] = __builtin_amdgcn_mfma_f32_16x16x32_bf16(afr[1], bfr, acc[1][ct], 0, 0, 0);
        }
    }

    float biasv[8];
    #pragma unroll
    for (int ct = 0; ct < 8; ++ct) biasv[ct] = bx[(ct << 4) + l15];

    #pragma unroll
    for (int rt = 0; rt < 2; ++rt) {
        #pragma unroll
        for (int j = 0; j < 4; ++j) {
            const int grow = m0 + (wid << 5) + (rt << 4) + (lq << 2) + j;
            if (grow < NNODES) {
                #pragma unroll
                for (int ct = 0; ct < 8; ++ct)
                    out[(size_t)grow * 128 + (ct << 4) + l15] =
                        (unsigned short)f2bf(acc[rt][ct][j] + biasv[ct]);
            }
        }
    }
}

// ---------------- per-layer GEMM: xw(bf16) = BNrelu(in_bf16) @ Wg[l] ----------------
// A staged in LDS (32 KB); B fragments read directly from L2-resident swizzled image.

__global__ __launch_bounds__(256) void k_gemm(const unsigned short* __restrict__ in,
                                              const char* __restrict__ wt,
                                              unsigned short* __restrict__ out,
                                              const float* __restrict__ bnsc,
                                              const float* __restrict__ bnsh,
                                              int apply_bn) {
    __shared__ char As[32768];   // 128 rows * 256 B, swizzled

    const int tid = threadIdx.x;
    const int m0 = blockIdx.x << 7;

    { // stage A: load bf16, BN+relu in fp32, back to bf16, swizzled ds_write
        const int c0 = (tid & 31) << 2;
        float sc0 = 1.f, sc1 = 1.f, sc2 = 1.f, sc3 = 1.f;
        float sh0 = 0.f, sh1 = 0.f, sh2 = 0.f, sh3 = 0.f;
        if (apply_bn) {
            sc0 = bnsc[c0]; sc1 = bnsc[c0 + 1]; sc2 = bnsc[c0 + 2]; sc3 = bnsc[c0 + 3];
            sh0 = bnsh[c0]; sh1 = bnsh[c0 + 1]; sh2 = bnsh[c0 + 2]; sh3 = bnsh[c0 + 3];
        }
        const int r0 = tid >> 5;
        #pragma unroll
        for (int it = 0; it < 16; ++it) {
            const int r = r0 + (it << 3);
            const int grow = m0 + r;
            uint2 p = {0u, 0u};
            if (grow < NNODES) {
                const uint2 raw = *(const uint2*)(in + (size_t)grow * 128 + c0);
                if (apply_bn) {
                    float x0 = fmaxf(fmaf(bf2f(raw.x & 0xffffu), sc0, sh0), 0.f);
                    float x1 = fmaxf(fmaf(bf2f(raw.x >> 16),     sc1, sh1), 0.f);
                    float x2 = fmaxf(fmaf(bf2f(raw.y & 0xffffu), sc2, sh2), 0.f);
                    float x3 = fmaxf(fmaf(bf2f(raw.y >> 16),     sc3, sh3), 0.f);
                    p.x = f2bf(x0) | (f2bf(x1) << 16);
                    p.y = f2bf(x2) | (f2bf(x3) << 16);
                } else {
                    p = raw;   // already bf16
                }
            }
            *(uint2*)(As + (r << 8) + ((c0 << 1) ^ ((r & 7) << 4))) = p;
        }
    }
    __syncthreads();

    const int lane = tid & 63;
    const int wid = tid >> 6;
    const int l15 = lane & 15;
    const int lq = lane >> 4;

    const f32x4 zero = {0.f, 0.f, 0.f, 0.f};
    f32x4 acc[2][8];
    #pragma unroll
    for (int i = 0; i < 2; ++i)
        #pragma unroll
        for (int j = 0; j < 8; ++j) acc[i][j] = zero;

    #pragma unroll
    for (int kk = 0; kk < 4; ++kk) {
        const int kb = (kk << 6) + (lq << 4);
        short8 afr[2];
        #pragma unroll
        for (int rt = 0; rt < 2; ++rt) {
            const int r = (wid << 5) + (rt << 4) + l15;
            afr[rt] = *(const short8*)(As + (r << 8) + (kb ^ ((r & 7) << 4)));
        }
        #pragma unroll
        for (int ct = 0; ct < 8; ++ct) {
            const int n = (ct << 4) + l15;
            const short8 bfr = *(const short8*)(wt + (n << 8) + (kb ^ ((n & 7) << 4)));
            acc[0][ct] = __builtin_amdgcn_mfma_f32_16x16x32_bf16(afr[0], bfr, acc[0][ct], 0, 0, 0);
            acc[1][ct] = __builtin_amdgcn_mfma_f32_16x16x32_bf16(afr[1], bfr, acc[1][ct], 0, 0, 0);
        }
    }

    #pragma unroll
    for (int rt = 0; rt < 2; ++rt) {
        #pragma unroll
        for (int j = 0; j < 4; ++j) {
            const int grow = m0 + (wid << 5) + (rt << 4) + (lq << 2) + j;
            if (grow < NNODES) {
                #pragma unroll
                for (int ct = 0; ct < 8; ++ct)
                    out[(size_t)grow * 128 + (ct << 4) + l15] =
                        (unsigned short)f2bf(acc[rt][ct][j]);
            }
        }
    }
}

// ------- aggregation: agg_l = bg + BNrelu(prev) + D^-1/2 A D^-1/2 xw ; fused BN stats -------
// 4 nodes per wave (16 lanes x 8 channels, uint4 loads) -> 4 independent gather chains.

__global__ __launch_bounds__(256) void k_agg(const unsigned short* __restrict__ prev,
                                             const unsigned short* __restrict__ xw,
                                             const float* __restrict__ dinv,
                                             const int* __restrict__ roff,
                                             const int2* __restrict__ cedge,
                                             const float* __restrict__ bg,
                                             const float* __restrict__ bnsc,
                                             const float* __restrict__ bnsh,
                                             int apply_bn,
                                             unsigned short* __restrict__ outb,
                                             float* __restrict__ stats) {
    const int lane = threadIdx.x & 63;
    const int wv   = threadIdx.x >> 6;       // wave 0..3
    const int g16  = lane >> 4;              // node slot within wave 0..3
    const int l16  = lane & 15;
    const int c8   = l16 << 3;               // channel base (8 channels per lane)

    float sc[8], sh[8], bgv[8];
    #pragma unroll
    for (int j = 0; j < 8; ++j) {
        sc[j] = apply_bn ? bnsc[c8 + j] : 1.f;
        sh[j] = apply_bn ? bnsh[c8 + j] : 0.f;
        bgv[j] = bg[c8 + j];
    }
    float s[8], q[8];
    #pragma unroll
    for (int j = 0; j < 8; ++j) { s[j] = 0.f; q[j] = 0.f; }

    const int stride = gridDim.x * 16;
    for (int v = blockIdx.x * 16 + wv * 4 + g16; v < NNODES; v += stride) {
        const int rof0 = roff[v];
        const int rof1 = roff[v + 1];
        const float dv = dinv[v];
        const uint4 resu  = *(const uint4*)(prev + (size_t)v * 128 + c8);
        const uint4 selfu = *(const uint4*)(xw + (size_t)v * 128 + c8);
        float a[8];
        {
            float r[8];
            r[0] = bf2f(resu.x & 0xffffu); r[1] = bf2f(resu.x >> 16);
            r[2] = bf2f(resu.y & 0xffffu); r[3] = bf2f(resu.y >> 16);
            r[4] = bf2f(resu.z & 0xffffu); r[5] = bf2f(resu.z >> 16);
            r[6] = bf2f(resu.w & 0xffffu); r[7] = bf2f(resu.w >> 16);
            if (apply_bn) {
                #pragma unroll
                for (int j = 0; j < 8; ++j)
                    a[j] = bgv[j] + fmaxf(fmaf(r[j], sc[j], sh[j]), 0.f);
            } else {
                #pragma unroll
                for (int j = 0; j < 8; ++j) a[j] = bgv[j] + r[j];
            }
            const float dvv = dv * dv;
            a[0] = fmaf(dvv, bf2f(selfu.x & 0xffffu), a[0]);
            a[1] = fmaf(dvv, bf2f(selfu.x >> 16), a[1]);
            a[2] = fmaf(dvv, bf2f(selfu.y & 0xffffu), a[2]);
            a[3] = fmaf(dvv, bf2f(selfu.y >> 16), a[3]);
            a[4] = fmaf(dvv, bf2f(selfu.z & 0xffffu), a[4]);
            a[5] = fmaf(dvv, bf2f(selfu.z >> 16), a[5]);
            a[6] = fmaf(dvv, bf2f(selfu.w & 0xffffu), a[6]);
            a[7] = fmaf(dvv, bf2f(selfu.w >> 16), a[7]);
        }
        for (int e = rof0; e < rof1; ++e) {
            const int2 ed = cedge[e];
            const float w = __int_as_float(ed.y);
            const uint4 gg = *(const uint4*)(xw + (size_t)ed.x * 128 + c8);
            a[0] = fmaf(w, bf2f(gg.x & 0xffffu), a[0]);
            a[1] = fmaf(w, bf2f(gg.x >> 16), a[1]);
            a[2] = fmaf(w, bf2f(gg.y & 0xffffu), a[2]);
            a[3] = fmaf(w, bf2f(gg.y >> 16), a[3]);
            a[4] = fmaf(w, bf2f(gg.z & 0xffffu), a[4]);
            a[5] = fmaf(w, bf2f(gg.z >> 16), a[5]);
            a[6] = fmaf(w, bf2f(gg.w & 0xffffu), a[6]);
            a[7] = fmaf(w, bf2f(gg.w >> 16), a[7]);
        }
        uint4 o;
        o.x = f2bf(a[0]) | (f2bf(a[1]) << 16);
        o.y = f2bf(a[2]) | (f2bf(a[3]) << 16);
        o.z = f2bf(a[4]) | (f2bf(a[5]) << 16);
        o.w = f2bf(a[6]) | (f2bf(a[7]) << 16);
        *(uint4*)(outb + (size_t)v * 128 + c8) = o;
        #pragma unroll
        for (int j = 0; j < 8; ++j) {
            s[j] += a[j];
            q[j] = fmaf(a[j], a[j], q[j]);
        }
    }

    // reduce the 4 node-groups within the wave: after xor16+xor32 every lane
    // holds the full-wave partial for its channel set (channels depend on l16 only)
    #pragma unroll
    for (int j = 0; j < 8; ++j) {
        s[j] += __shfl_xor(s[j], 16); s[j] += __shfl_xor(s[j], 32);
        q[j] += __shfl_xor(q[j], 16); q[j] += __shfl_xor(q[j], 32);
    }
    __shared__ float red[512];
    if (g16 == 0) {
        #pragma unroll
        for (int j = 0; j < 8; ++j) red[wv * 128 + c8 + j] = s[j];
    }
    __syncthreads();
    if (threadIdx.x < 128) {
        const int ch = threadIdx.x;
        atomicAdd(&stats[ch], red[ch] + red[128 + ch] + red[256 + ch] + red[384 + ch]);
    }
    __syncthreads();
    if (g16 == 0) {
        #pragma unroll
        for (int j = 0; j < 8; ++j) red[wv * 128 + c8 + j] = q[j];
    }
    __syncthreads();
    if (threadIdx.x < 128) {
        const int ch = threadIdx.x;
        atomicAdd(&stats[128 + ch], red[ch] + red[128 + ch] + red[256 + ch] + red[384 + ch]);
    }
}

__global__ void k_bnfin(const float* __restrict__ stats, const float* __restrict__ gamma,
                        const float* __restrict__ beta, float* __restrict__ sc,
                        float* __restrict__ sh) {
    int c = threadIdx.x;
    const float inv_n = 1.f / (float)NNODES;
    float mean = stats[c] * inv_n;
    float var = stats[128 + c] * inv_n - mean * mean;
    float s = gamma[c] * rsqrtf(var + BN_EPS);
    sc[c] = s;
    sh[c] = fmaf(-mean, s, beta[c]);
}

// ---------------- pooling (sorted batch ranges) + readout MLP ----------------

__global__ __launch_bounds__(128) void k_pool(const unsigned short* __restrict__ agg,
                                              const float* __restrict__ bnsc,
                                              const float* __restrict__ bnsh,
                                              const int* __restrict__ gstart,
                                              const float* __restrict__ W1, const float* __restrict__ b1,
                                              const float* __restrict__ W2, const float* __restrict__ b2,
                                              const float* __restrict__ W3, const float* __restrict__ b3,
                                              float* __restrict__ out) {
    __shared__ float mol[128];
    __shared__ float h1s[128];
    const int g = blockIdx.x;
    const int c = threadIdx.x;
    const float sc = bnsc[c], sh = bnsh[c];
    const int v0 = gstart[g], v1 = gstart[g + 1];
    float acc = 0.f;
    for (int v = v0; v < v1; ++v)
        acc += fmaf(bf2f(agg[(size_t)v * 128 + c]), sc, sh);  // last layer: BN, no relu
    mol[c] = acc;
    __syncthreads();
    float a1 = b1[c];
    #pragma unroll 8
    for (int k = 0; k < 128; ++k) a1 = fmaf(mol[k], W1[k * 128 + c], a1);
    h1s[c] = fmaxf(a1, 0.f);
    __syncthreads();
    if (c < 64) {
        float a2 = b2[c];
        #pragma unroll 8
        for (int k = 0; k < 128; ++k) a2 = fmaf(h1s[k], W2[k * 64 + c], a2);
        float p = fmaxf(a2, 0.f) * W3[c];
        #pragma unroll
        for (int o = 32; o > 0; o >>= 1) p += __shfl_down(p, o);
        if (c == 0) out[g] = p + b3[0];
    }
}

// ---------------- launch ----------------

extern "C" void kernel_launch(void* const* d_in, const int* in_sizes, int n_in,
                              void* d_out, int out_size, void* d_ws, size_t ws_size,
                              hipStream_t stream) {
    (void)in_sizes; (void)n_in; (void)out_size; (void)ws_size;
    const float* x     = (const float*)d_in[0];
    const int*   ei    = (const int*)d_in[1];
    const int*   batch = (const int*)d_in[2];
    const float* Wx    = (const float*)d_in[3];
    const float* bx    = (const float*)d_in[4];
    const float* Wg    = (const float*)d_in[5];
    const float* bg    = (const float*)d_in[6];
    const float* gamma = (const float*)d_in[7];
    const float* beta  = (const float*)d_in[8];
    const float* W1    = (const float*)d_in[9];
    const float* b1    = (const float*)d_in[10];
    const float* W2    = (const float*)d_in[11];
    const float* b2    = (const float*)d_in[12];
    const float* W3    = (const float*)d_in[13];
    const float* b3    = (const float*)d_in[14];
    float* out = (float*)d_out;

    char* ws = (char*)d_ws;
    size_t off = 0;
    auto alloc = [&](size_t bytes) -> char* {
        char* p = ws + off;
        off += (bytes + 255) & ~(size_t)255;
        return p;
    };
    unsigned short* aggA   = (unsigned short*)alloc((size_t)NNODES * 128 * 2);
    unsigned short* aggB   = (unsigned short*)alloc((size_t)NNODES * 128 * 2);
    unsigned short* xw     = (unsigned short*)alloc((size_t)NNODES * 128 * 2);
    float*          dinv   = (float*)alloc((size_t)NNODES * 4);
    int*            cnt    = (int*)alloc((size_t)NNODES * 4);
    int*            cursor = (int*)alloc((size_t)NNODES * 4);
    int*            roff   = (int*)alloc((size_t)(NNODES + 1) * 4);
    int2*           cedge  = (int2*)alloc((size_t)NEDGES * 8);
    char*           wt     = alloc((size_t)NLAYERS * 32768);
    char*           wxt    = alloc((size_t)16384);
    float*          stats  = (float*)alloc((size_t)NLAYERS * 256 * 4);
    float*          bnsc   = (float*)alloc((size_t)NLAYERS * 128 * 4);
    float*          bnsh   = (float*)alloc((size_t)NLAYERS * 128 * 4);
    int*            gstart = (int*)alloc((size_t)(NGRAPHS + 1) * 4);
    int*            bsum   = (int*)alloc((size_t)1024 * 4);

    const int NB = (NNODES + 255) / 256;   // 782
    const int EB = (NEDGES + 255) / 256;   // 1563
    const int GB = (NNODES + 127) / 128;   // 1563 gemm tiles
    const int WB = (NLAYERS * 16384 + 8192 + 255) / 256;

    k_init<<<NB, 256, 0, stream>>>(cnt, cursor, stats);
    k_count<<<EB, 256, 0, stream>>>(ei, cnt);
    k_dinv<<<NB, 256, 0, stream>>>(cnt, dinv);
    k_scan1<<<NB, 256, 0, stream>>>(cnt, roff, bsum);
    k_scan2<<<1, 1024, 0, stream>>>(bsum, NB);
    k_scan3<<<NB, 256, 0, stream>>>(roff, bsum);
    k_fill<<<EB, 256, 0, stream>>>(ei, dinv, roff, cursor, cedge);
    k_ranges<<<NB, 256, 0, stream>>>(batch, gstart);
    k_wtrans<<<WB, 256, 0, stream>>>(Wg, Wx, wt, wxt);
    k_inproj<<<GB, 256, 0, stream>>>(x, wxt, bx, aggA);

    unsigned short* cur = aggA;
    unsigned short* nxt = aggB;
    for (int l = 0; l < NLAYERS; ++l) {
        const float* psc = (l > 0) ? (bnsc + (l - 1) * 128) : (const float*)nullptr;
        const float* psh = (l > 0) ? (bnsh + (l - 1) * 128) : (const float*)nullptr;
        k_gemm<<<GB, 256, 0, stream>>>(cur, wt + (size_t)l * 32768, xw,
                                       psc, psh, l > 0);
        k_agg<<<2048, 256, 0, stream>>>(cur, xw, dinv, roff, cedge,
                                        bg + l * 128, psc, psh, l > 0,
                                        nxt, stats + l * 256);
        k_bnfin<<<1, 128, 0, stream>>>(stats + l * 256, gamma + l * 128, beta + l * 128,
                                       bnsc + l * 128, bnsh + l * 128);
        unsigned short* t = cur; cur = nxt; nxt = t;
    }

    k_pool<<<NGRAPHS, 128, 0, stream>>>(cur, bnsc + 4 * 128, bnsh + 4 * 128, gstart,
                                        W1, b1, W2, b2, W3, b3, out);
}

// Round 6
// 827.582 us; speedup vs baseline: 1.0568x; 1.0568x over previous
//
#include <hip/hip_runtime.h>
#include <stdint.h>

#define NNODES  200000
#define NEDGES  400000
#define NGRAPHS 4000
#define NLAYERS 5
#define BN_EPS  1e-5f

typedef __attribute__((ext_vector_type(8))) short short8;
typedef __attribute__((ext_vector_type(4))) float f32x4;

__device__ __forceinline__ unsigned int f2bf(float f) {
    unsigned int u = __float_as_uint(f);
    return (u + 0x7fffu + ((u >> 16) & 1u)) >> 16;
}
__device__ __forceinline__ float bf2f(unsigned int b) {
    return __uint_as_float(b << 16);
}

// accumulate 8 bf16 channels from a uint4 gather with weight wgt (inline fn, not
// a macro: macro param named `w` collided with the `.w` member token in R5)
__device__ __forceinline__ void acc8(float (&a)[8], float wgt, const uint4& g) {
    a[0] = fmaf(wgt, bf2f(g.x & 0xffffu), a[0]);
    a[1] = fmaf(wgt, bf2f(g.x >> 16),     a[1]);
    a[2] = fmaf(wgt, bf2f(g.y & 0xffffu), a[2]);
    a[3] = fmaf(wgt, bf2f(g.y >> 16),     a[3]);
    a[4] = fmaf(wgt, bf2f(g.z & 0xffffu), a[4]);
    a[5] = fmaf(wgt, bf2f(g.z >> 16),     a[5]);
    a[6] = fmaf(wgt, bf2f(g.w & 0xffffu), a[6]);
    a[7] = fmaf(wgt, bf2f(g.w >> 16),     a[7]);
}

// ---------------- graph prep ----------------

__global__ void k_init(int* __restrict__ cnt, int* __restrict__ cursor, float* __restrict__ stats) {
    int i = blockIdx.x * 256 + threadIdx.x;
    if (i < NNODES) { cnt[i] = 0; cursor[i] = 0; }
    if (i < NLAYERS * 256) stats[i] = 0.f;
}

__global__ void k_count(const int* __restrict__ ei, int* __restrict__ cnt) {
    int e = blockIdx.x * 256 + threadIdx.x;
    if (e < NEDGES) atomicAdd(&cnt[ei[NEDGES + e]], 1);
}

__global__ void k_dinv(const int* __restrict__ cnt, float* __restrict__ dinv) {
    int v = blockIdx.x * 256 + threadIdx.x;
    if (v < NNODES) dinv[v] = rsqrtf((float)cnt[v] + 1.0f);
}

__global__ __launch_bounds__(256) void k_scan1(const int* __restrict__ cnt,
                                               int* __restrict__ roff, int* __restrict__ bsum) {
    __shared__ int s[256];
    int t = threadIdx.x;
    int v = blockIdx.x * 256 + t;
    int val = (v < NNODES) ? cnt[v] : 0;
    s[t] = val; __syncthreads();
    int sum = val;
    for (int o = 1; o < 256; o <<= 1) {
        int tmp = (t >= o) ? s[t - o] : 0;
        __syncthreads();
        sum += tmp; s[t] = sum;
        __syncthreads();
    }
    if (v < NNODES) roff[v] = sum - val;       // exclusive within block
    if (t == 255) bsum[blockIdx.x] = s[255];
}

__global__ __launch_bounds__(1024) void k_scan2(int* __restrict__ bsum, int nb) {
    __shared__ int s[1024];
    int t = threadIdx.x;
    int val = (t < nb) ? bsum[t] : 0;
    s[t] = val; __syncthreads();
    int sum = val;
    for (int o = 1; o < 1024; o <<= 1) {
        int tmp = (t >= o) ? s[t - o] : 0;
        __syncthreads();
        sum += tmp; s[t] = sum;
        __syncthreads();
    }
    if (t < nb) bsum[t] = sum - val;           // exclusive block offsets
}

__global__ void k_scan3(int* __restrict__ roff, const int* __restrict__ bsum) {
    int v = blockIdx.x * 256 + threadIdx.x;
    if (v < NNODES) roff[v] += bsum[blockIdx.x];
    if (v == 0) roff[NNODES] = NEDGES;
}

__global__ void k_fill(const int* __restrict__ ei, const float* __restrict__ dinv,
                       const int* __restrict__ roff, int* __restrict__ cursor,
                       int2* __restrict__ cedge) {
    int e = blockIdx.x * 256 + threadIdx.x;
    if (e >= NEDGES) return;
    int s = ei[e], d = ei[NEDGES + e];
    int pos = atomicAdd(&cursor[d], 1);
    int idx = roff[d] + pos;
    int2 ed; ed.x = s; ed.y = __float_as_int(dinv[s] * dinv[d]);
    cedge[idx] = ed;
}

__global__ void k_ranges(const int* __restrict__ batch, int* __restrict__ gstart) {
    int v = blockIdx.x * 256 + threadIdx.x;
    if (v >= NNODES) return;
    int b = batch[v];
    if (v == 0) {
        for (int g = 0; g <= b; ++g) gstart[g] = 0;
    } else {
        int pb = batch[v - 1];
        for (int g = pb + 1; g <= b; ++g) gstart[g] = v;
    }
    if (v == NNODES - 1) {
        for (int g = b + 1; g <= NGRAPHS; ++g) gstart[g] = NNODES;
    }
}

// transpose + bf16-convert + swizzle layer weights WT[n][k]=W[k][n] (256B rows),
// and Wx -> WxT[n][k0..63] zero-padded (128B rows), with bias folded at k=40.
__global__ void k_wtrans(const float* __restrict__ Wg, const float* __restrict__ Wx,
                         const float* __restrict__ bx,
                         char* __restrict__ wt, char* __restrict__ wxt) {
    int idx = blockIdx.x * 256 + threadIdx.x;
    if (idx < NLAYERS * 16384) {
        int l = idx >> 14;
        int rem = idx & 16383;
        int n = rem >> 7;
        int k = rem & 127;
        float v = Wg[l * 16384 + k * 128 + n];
        char* img = wt + l * 32768;
        *(unsigned short*)(img + (n << 8) + ((k << 1) ^ ((n & 7) << 4))) = (unsigned short)f2bf(v);
    } else if (idx < NLAYERS * 16384 + 8192) {
        int j = idx - NLAYERS * 16384;
        int n = j >> 6;
        int k = j & 63;
        float v = (k < 40) ? Wx[k * 128 + n] : (k == 40 ? bx[n] : 0.f);
        *(unsigned short*)(wxt + (n << 7) + ((k << 1) ^ ((n & 7) << 4))) = (unsigned short)f2bf(v);
    }
}

// ---------------- input projection (MFMA): h0 = bf16(x @ Wx + bx) ----------------
// K=40 padded to 64 with homogeneous 1.0 at k=40 (bias row). Swapped-operand MFMA:
// D[channel][node] so each lane stores 4 consecutive channels per node (uint2).

__global__ __launch_bounds__(256) void k_inproj(const float* __restrict__ x,
                                                const char* __restrict__ wxt,
                                                unsigned short* __restrict__ out) {
    __shared__ char As[16384];   // 128 rows * 128 B
    const int tid = threadIdx.x;
    const int m0 = blockIdx.x << 7;

    { // stage A: 16 threads per row cover k 0..63 (4 each); k=40 -> 1.0
        const int kq = (tid & 15) << 2;   // 0,4,...,60
        const int r0 = tid >> 4;          // 0..15
        #pragma unroll
        for (int it = 0; it < 8; ++it) {
            const int r = r0 + (it << 4);
            const int grow = m0 + r;
            float x0 = 0.f, x1 = 0.f, x2 = 0.f, x3 = 0.f;
            if (grow < NNODES) {
                if (kq < 40) {
                    const float4 v = *(const float4*)(x + (size_t)grow * 40 + kq);
                    x0 = v.x; x1 = v.y; x2 = v.z; x3 = v.w;
                } else if (kq == 40) {
                    x0 = 1.0f;   // homogeneous coordinate -> bias via MFMA
                }
            }
            uint2 p;
            p.x = f2bf(x0) | (f2bf(x1) << 16);
            p.y = f2bf(x2) | (f2bf(x3) << 16);
            *(uint2*)(As + (r << 7) + ((kq << 1) ^ ((r & 7) << 4))) = p;
        }
    }
    __syncthreads();

    const int lane = tid & 63;
    const int wid = tid >> 6;
    const int l15 = lane & 15;
    const int lq = lane >> 4;

    const f32x4 zero = {0.f, 0.f, 0.f, 0.f};
    f32x4 acc[2][8];
    #pragma unroll
    for (int i = 0; i < 2; ++i)
        #pragma unroll
        for (int j = 0; j < 8; ++j) acc[i][j] = zero;

    #pragma unroll
    for (int kk = 0; kk < 2; ++kk) {
        const int kb = (kk << 6) + (lq << 4);
        short8 afr[2];
        #pragma unroll
        for (int rt = 0; rt < 2; ++rt) {
            const int r = (wid << 5) + (rt << 4) + l15;
            afr[rt] = *(const short8*)(As + (r << 7) + (kb ^ ((r & 7) << 4)));
        }
        #pragma unroll
        for (int ct = 0; ct < 8; ++ct) {
            const int n = (ct << 4) + l15;
            const short8 bfr = *(const short8*)(wxt + (n << 7) + (kb ^ ((n & 7) << 4)));
            // swapped operands: D[channel][node]
            acc[0][ct] = __builtin_amdgcn_mfma_f32_16x16x32_bf16(bfr, afr[0], acc[0][ct], 0, 0, 0);
            acc[1][ct] = __builtin_amdgcn_mfma_f32_16x16x32_bf16(bfr, afr[1], acc[1][ct], 0, 0, 0);
        }
    }

    #pragma unroll
    for (int rt = 0; rt < 2; ++rt) {
        const int grow = m0 + (wid << 5) + (rt << 4) + l15;   // node
        if (grow < NNODES) {
            #pragma unroll
            for (int ct = 0; ct < 8; ++ct) {
                uint2 pk;
                pk.x = f2bf(acc[rt][ct][0]) | (f2bf(acc[rt][ct][1]) << 16);
                pk.y = f2bf(acc[rt][ct][2]) | (f2bf(acc[rt][ct][3]) << 16);
                *(uint2*)(out + (size_t)grow * 128 + (ct << 4) + (lq << 2)) = pk;
            }
        }
    }
}

// ---------------- per-layer GEMM: xw(bf16) = BNrelu(in_bf16) @ Wg[l] ----------------
// A staged in LDS; W^T fragments from L2-resident swizzled image; swapped-operand
// MFMA gives D[channel][node] -> uint2 stores (4 channels/lane contiguous).

__global__ __launch_bounds__(256) void k_gemm(const unsigned short* __restrict__ in,
                                              const char* __restrict__ wt,
                                              unsigned short* __restrict__ out,
                                              const float* __restrict__ bnsc,
                                              const float* __restrict__ bnsh,
                                              int apply_bn) {
    __shared__ char As[32768];   // 128 rows * 256 B, swizzled

    const int tid = threadIdx.x;
    const int m0 = blockIdx.x << 7;

    { // stage A: load bf16, BN+relu in fp32, back to bf16, swizzled ds_write
        const int c0 = (tid & 31) << 2;
        float sc0 = 1.f, sc1 = 1.f, sc2 = 1.f, sc3 = 1.f;
        float sh0 = 0.f, sh1 = 0.f, sh2 = 0.f, sh3 = 0.f;
        if (apply_bn) {
            sc0 = bnsc[c0]; sc1 = bnsc[c0 + 1]; sc2 = bnsc[c0 + 2]; sc3 = bnsc[c0 + 3];
            sh0 = bnsh[c0]; sh1 = bnsh[c0 + 1]; sh2 = bnsh[c0 + 2]; sh3 = bnsh[c0 + 3];
        }
        const int r0 = tid >> 5;
        #pragma unroll
        for (int it = 0; it < 16; ++it) {
            const int r = r0 + (it << 3);
            const int grow = m0 + r;
            uint2 p = {0u, 0u};
            if (grow < NNODES) {
                const uint2 raw = *(const uint2*)(in + (size_t)grow * 128 + c0);
                if (apply_bn) {
                    float x0 = fmaxf(fmaf(bf2f(raw.x & 0xffffu), sc0, sh0), 0.f);
                    float x1 = fmaxf(fmaf(bf2f(raw.x >> 16),     sc1, sh1), 0.f);
                    float x2 = fmaxf(fmaf(bf2f(raw.y & 0xffffu), sc2, sh2), 0.f);
                    float x3 = fmaxf(fmaf(bf2f(raw.y >> 16),     sc3, sh3), 0.f);
                    p.x = f2bf(x0) | (f2bf(x1) << 16);
                    p.y = f2bf(x2) | (f2bf(x3) << 16);
                } else {
                    p = raw;   // already bf16
                }
            }
            *(uint2*)(As + (r << 8) + ((c0 << 1) ^ ((r & 7) << 4))) = p;
        }
    }
    __syncthreads();

    const int lane = tid & 63;
    const int wid = tid >> 6;
    const int l15 = lane & 15;
    const int lq = lane >> 4;

    const f32x4 zero = {0.f, 0.f, 0.f, 0.f};
    f32x4 acc[2][8];
    #pragma unroll
    for (int i = 0; i < 2; ++i)
        #pragma unroll
        for (int j = 0; j < 8; ++j) acc[i][j] = zero;

    #pragma unroll
    for (int kk = 0; kk < 4; ++kk) {
        const int kb = (kk << 6) + (lq << 4);
        short8 afr[2];
        #pragma unroll
        for (int rt = 0; rt < 2; ++rt) {
            const int r = (wid << 5) + (rt << 4) + l15;
            afr[rt] = *(const short8*)(As + (r << 8) + (kb ^ ((r & 7) << 4)));
        }
        #pragma unroll
        for (int ct = 0; ct < 8; ++ct) {
            const int n = (ct << 4) + l15;
            const short8 bfr = *(const short8*)(wt + (n << 8) + (kb ^ ((n & 7) << 4)));
            // swapped operands: D[channel][node]
            acc[0][ct] = __builtin_amdgcn_mfma_f32_16x16x32_bf16(bfr, afr[0], acc[0][ct], 0, 0, 0);
            acc[1][ct] = __builtin_amdgcn_mfma_f32_16x16x32_bf16(bfr, afr[1], acc[1][ct], 0, 0, 0);
        }
    }

    #pragma unroll
    for (int rt = 0; rt < 2; ++rt) {
        const int grow = m0 + (wid << 5) + (rt << 4) + l15;   // node
        if (grow < NNODES) {
            #pragma unroll
            for (int ct = 0; ct < 8; ++ct) {
                uint2 pk;
                pk.x = f2bf(acc[rt][ct][0]) | (f2bf(acc[rt][ct][1]) << 16);
                pk.y = f2bf(acc[rt][ct][2]) | (f2bf(acc[rt][ct][3]) << 16);
                *(uint2*)(out + (size_t)grow * 128 + (ct << 4) + (lq << 2)) = pk;
            }
        }
    }
}

// ------- aggregation: agg_l = bg + BNrelu(prev) + D^-1/2 A D^-1/2 xw ; fused BN stats -------
// 4 nodes per wave (16 lanes x 8 channels); edge loop batched x4: 4 independent
// gathers in flight per slot (16 per wave). Degree padding uses weight-0 dup gathers.

__global__ __launch_bounds__(256) void k_agg(const unsigned short* __restrict__ prev,
                                             const unsigned short* __restrict__ xw,
                                             const float* __restrict__ dinv,
                                             const int* __restrict__ roff,
                                             const int2* __restrict__ cedge,
                                             const float* __restrict__ bg,
                                             const float* __restrict__ bnsc,
                                             const float* __restrict__ bnsh,
                                             int apply_bn,
                                             unsigned short* __restrict__ outb,
                                             float* __restrict__ stats) {
    const int lane = threadIdx.x & 63;
    const int wv   = threadIdx.x >> 6;       // wave 0..3
    const int g16  = lane >> 4;              // node slot within wave 0..3
    const int l16  = lane & 15;
    const int c8   = l16 << 3;               // channel base (8 channels per lane)

    float sc[8], sh[8], bgv[8];
    #pragma unroll
    for (int j = 0; j < 8; ++j) {
        sc[j] = apply_bn ? bnsc[c8 + j] : 1.f;
        sh[j] = apply_bn ? bnsh[c8 + j] : 0.f;
        bgv[j] = bg[c8 + j];
    }
    float s[8], q[8];
    #pragma unroll
    for (int j = 0; j < 8; ++j) { s[j] = 0.f; q[j] = 0.f; }

    const int stride = gridDim.x * 16;
    for (int v = blockIdx.x * 16 + wv * 4 + g16; v < NNODES; v += stride) {
        const int rof0 = roff[v];
        const int rof1 = roff[v + 1];
        const float dv = dinv[v];
        const uint4 resu  = *(const uint4*)(prev + (size_t)v * 128 + c8);
        const uint4 selfu = *(const uint4*)(xw + (size_t)v * 128 + c8);
        float a[8];
        {
            float r[8];
            r[0] = bf2f(resu.x & 0xffffu); r[1] = bf2f(resu.x >> 16);
            r[2] = bf2f(resu.y & 0xffffu); r[3] = bf2f(resu.y >> 16);
            r[4] = bf2f(resu.z & 0xffffu); r[5] = bf2f(resu.z >> 16);
            r[6] = bf2f(resu.w & 0xffffu); r[7] = bf2f(resu.w >> 16);
            if (apply_bn) {
                #pragma unroll
                for (int j = 0; j < 8; ++j)
                    a[j] = bgv[j] + fmaxf(fmaf(r[j], sc[j], sh[j]), 0.f);
            } else {
                #pragma unroll
                for (int j = 0; j < 8; ++j) a[j] = bgv[j] + r[j];
            }
            acc8(a, dv * dv, selfu);
        }
        int e = rof0;
        while (e < rof1) {
            const int rem = rof1 - e;
            const int2 d0 = cedge[e];
            const int2 d1 = cedge[rem > 1 ? e + 1 : e];
            const int2 d2 = cedge[rem > 2 ? e + 2 : e];
            const int2 d3 = cedge[rem > 3 ? e + 3 : e];
            const float w0 = __int_as_float(d0.y);
            const float w1 = rem > 1 ? __int_as_float(d1.y) : 0.f;
            const float w2 = rem > 2 ? __int_as_float(d2.y) : 0.f;
            const float w3 = rem > 3 ? __int_as_float(d3.y) : 0.f;
            const uint4 g0 = *(const uint4*)(xw + (size_t)d0.x * 128 + c8);
            const uint4 g1 = *(const uint4*)(xw + (size_t)d1.x * 128 + c8);
            const uint4 g2 = *(const uint4*)(xw + (size_t)d2.x * 128 + c8);
            const uint4 g3 = *(const uint4*)(xw + (size_t)d3.x * 128 + c8);
            acc8(a, w0, g0);
            acc8(a, w1, g1);
            acc8(a, w2, g2);
            acc8(a, w3, g3);
            e += 4;
        }
        uint4 o;
        o.x = f2bf(a[0]) | (f2bf(a[1]) << 16);
        o.y = f2bf(a[2]) | (f2bf(a[3]) << 16);
        o.z = f2bf(a[4]) | (f2bf(a[5]) << 16);
        o.w = f2bf(a[6]) | (f2bf(a[7]) << 16);
        *(uint4*)(outb + (size_t)v * 128 + c8) = o;
        #pragma unroll
        for (int j = 0; j < 8; ++j) {
            s[j] += a[j];
            q[j] = fmaf(a[j], a[j], q[j]);
        }
    }

    // combine the 4 node-slots (channels depend on l16 only)
    #pragma unroll
    for (int j = 0; j < 8; ++j) {
        s[j] += __shfl_xor(s[j], 16); s[j] += __shfl_xor(s[j], 32);
        q[j] += __shfl_xor(q[j], 16); q[j] += __shfl_xor(q[j], 32);
    }
    __shared__ float red[512];
    if (g16 == 0) {
        #pragma unroll
        for (int j = 0; j < 8; ++j) red[wv * 128 + c8 + j] = s[j];
    }
    __syncthreads();
    if (threadIdx.x < 128) {
        const int ch = threadIdx.x;
        atomicAdd(&stats[ch], red[ch] + red[128 + ch] + red[256 + ch] + red[384 + ch]);
    }
    __syncthreads();
    if (g16 == 0) {
        #pragma unroll
        for (int j = 0; j < 8; ++j) red[wv * 128 + c8 + j] = q[j];
    }
    __syncthreads();
    if (threadIdx.x < 128) {
        const int ch = threadIdx.x;
        atomicAdd(&stats[128 + ch], red[ch] + red[128 + ch] + red[256 + ch] + red[384 + ch]);
    }
}

__global__ void k_bnfin(const float* __restrict__ stats, const float* __restrict__ gamma,
                        const float* __restrict__ beta, float* __restrict__ sc,
                        float* __restrict__ sh) {
    int c = threadIdx.x;
    const float inv_n = 1.f / (float)NNODES;
    float mean = stats[c] * inv_n;
    float var = stats[128 + c] * inv_n - mean * mean;
    float s = gamma[c] * rsqrtf(var + BN_EPS);
    sc[c] = s;
    sh[c] = fmaf(-mean, s, beta[c]);
}

// ---------------- pooling (sorted batch ranges) + readout MLP ----------------

__global__ __launch_bounds__(128) void k_pool(const unsigned short* __restrict__ agg,
                                              const float* __restrict__ bnsc,
                                              const float* __restrict__ bnsh,
                                              const int* __restrict__ gstart,
                                              const float* __restrict__ W1, const float* __restrict__ b1,
                                              const float* __restrict__ W2, const float* __restrict__ b2,
                                              const float* __restrict__ W3, const float* __restrict__ b3,
                                              float* __restrict__ out) {
    __shared__ float mol[128];
    __shared__ float h1s[128];
    const int g = blockIdx.x;
    const int c = threadIdx.x;
    const float sc = bnsc[c], sh = bnsh[c];
    const int v0 = gstart[g], v1 = gstart[g + 1];
    float acc = 0.f;
    for (int v = v0; v < v1; ++v)
        acc += fmaf(bf2f(agg[(size_t)v * 128 + c]), sc, sh);  // last layer: BN, no relu
    mol[c] = acc;
    __syncthreads();
    float a1 = b1[c];
    #pragma unroll 8
    for (int k = 0; k < 128; ++k) a1 = fmaf(mol[k], W1[k * 128 + c], a1);
    h1s[c] = fmaxf(a1, 0.f);
    __syncthreads();
    if (c < 64) {
        float a2 = b2[c];
        #pragma unroll 8
        for (int k = 0; k < 128; ++k) a2 = fmaf(h1s[k], W2[k * 64 + c], a2);
        float p = fmaxf(a2, 0.f) * W3[c];
        #pragma unroll
        for (int o = 32; o > 0; o >>= 1) p += __shfl_down(p, o);
        if (c == 0) out[g] = p + b3[0];
    }
}

// ---------------- launch ----------------

extern "C" void kernel_launch(void* const* d_in, const int* in_sizes, int n_in,
                              void* d_out, int out_size, void* d_ws, size_t ws_size,
                              hipStream_t stream) {
    (void)in_sizes; (void)n_in; (void)out_size; (void)ws_size;
    const float* x     = (const float*)d_in[0];
    const int*   ei    = (const int*)d_in[1];
    const int*   batch = (const int*)d_in[2];
    const float* Wx    = (const float*)d_in[3];
    const float* bx    = (const float*)d_in[4];
    const float* Wg    = (const float*)d_in[5];
    const float* bg    = (const float*)d_in[6];
    const float* gamma = (const float*)d_in[7];
    const float* beta  = (const float*)d_in[8];
    const float* W1    = (const float*)d_in[9];
    const float* b1    = (const float*)d_in[10];
    const float* W2    = (const float*)d_in[11];
    const float* b2    = (const float*)d_in[12];
    const float* W3    = (const float*)d_in[13];
    const float* b3    = (const float*)d_in[14];
    float* out = (float*)d_out;

    char* ws = (char*)d_ws;
    size_t off = 0;
    auto alloc = [&](size_t bytes) -> char* {
        char* p = ws + off;
        off += (bytes + 255) & ~(size_t)255;
        return p;
    };
    unsigned short* aggA   = (unsigned short*)alloc((size_t)NNODES * 128 * 2);
    unsigned short* aggB   = (unsigned short*)alloc((size_t)NNODES * 128 * 2);
    unsigned short* xw     = (unsigned short*)alloc((size_t)NNODES * 128 * 2);
    float*          dinv   = (float*)alloc((size_t)NNODES * 4);
    int*            cnt    = (int*)alloc((size_t)NNODES * 4);
    int*            cursor = (int*)alloc((size_t)NNODES * 4);
    int*            roff   = (int*)alloc((size_t)(NNODES + 1) * 4);
    int2*           cedge  = (int2*)alloc((size_t)NEDGES * 8);
    char*           wt     = alloc((size_t)NLAYERS * 32768);
    char*           wxt    = alloc((size_t)16384);
    float*          stats  = (float*)alloc((size_t)NLAYERS * 256 * 4);
    float*          bnsc   = (float*)alloc((size_t)NLAYERS * 128 * 4);
    float*          bnsh   = (float*)alloc((size_t)NLAYERS * 128 * 4);
    int*            gstart = (int*)alloc((size_t)(NGRAPHS + 1) * 4);
    int*            bsum   = (int*)alloc((size_t)1024 * 4);

    const int NB = (NNODES + 255) / 256;   // 782
    const int EB = (NEDGES + 255) / 256;   // 1563
    const int GB = (NNODES + 127) / 128;   // 1563 gemm tiles
    const int WB = (NLAYERS * 16384 + 8192 + 255) / 256;

    k_init<<<NB, 256, 0, stream>>>(cnt, cursor, stats);
    k_count<<<EB, 256, 0, stream>>>(ei, cnt);
    k_dinv<<<NB, 256, 0, stream>>>(cnt, dinv);
    k_scan1<<<NB, 256, 0, stream>>>(cnt, roff, bsum);
    k_scan2<<<1, 1024, 0, stream>>>(bsum, NB);
    k_scan3<<<NB, 256, 0, stream>>>(roff, bsum);
    k_fill<<<EB, 256, 0, stream>>>(ei, dinv, roff, cursor, cedge);
    k_ranges<<<NB, 256, 0, stream>>>(batch, gstart);
    k_wtrans<<<WB, 256, 0, stream>>>(Wg, Wx, bx, wt, wxt);
    k_inproj<<<GB, 256, 0, stream>>>(x, wxt, aggA);

    unsigned short* cur = aggA;
    unsigned short* nxt = aggB;
    for (int l = 0; l < NLAYERS; ++l) {
        const float* psc = (l > 0) ? (bnsc + (l - 1) * 128) : (const float*)nullptr;
        const float* psh = (l > 0) ? (bnsh + (l - 1) * 128) : (const float*)nullptr;
        k_gemm<<<GB, 256, 0, stream>>>(cur, wt + (size_t)l * 32768, xw,
                                       psc, psh, l > 0);
        k_agg<<<2048, 256, 0, stream>>>(cur, xw, dinv, roff, cedge,
                                        bg + l * 128, psc, psh, l > 0,
                                        nxt, stats + l * 256);
        k_bnfin<<<1, 128, 0, stream>>>(stats + l * 256, gamma + l * 128, beta + l * 128,
                                       bnsc + l * 128, bnsh + l * 128);
        unsigned short* t = cur; cur = nxt; nxt = t;
    }

    k_pool<<<NGRAPHS, 128, 0, stream>>>(cur, bnsc + 4 * 128, bnsh + 4 * 128, gstart,
                                        W1, b1, W2, b2, W3, b3, out);
}